// Round 5
// baseline (649.144 us; speedup 1.0000x reference)
//
#include <hip/hip_runtime.h>
#include <hip/hip_bf16.h>

// Transformer block: x:[8,2048,768] fp32. All GEMMs in bf16 MFMA (fp32 acc).
// GEMM: 128x128x64 tiles, 32x32x16 MFMA (2x2/wave), global_load_lds dwordx4,
// phase-aware XOR swizzle (c ^ (r&7) ^ ((r>>3)&3)), XCD block swizzle, lb(256,4).
// Workspace layout (bytes):
//   [0          ) xn / xn2 bf16        25,165,824
//   [25165824   ) QK bf16 [16384][1536] 50,331,648   (aliased later by h1)
//   [75497472   ) vT bf16 [8][768][2048] 25,165,824  (h1)
//   [100663296  ) S/P bf16 [8][2048][2048] 67,108,864 (h1 overlaps; xb after PV)
//   [167772160  ) y bf16               25,165,824
//   [192937984  ) bf16 weights         14,155,776
// total: 207,093,760 bytes

typedef unsigned short u16;
typedef __bf16 bf16x8 __attribute__((ext_vector_type(8)));
typedef float  f32x4  __attribute__((ext_vector_type(4)));
typedef float  f32x16 __attribute__((ext_vector_type(16)));
typedef int    i32x4  __attribute__((ext_vector_type(4)));
typedef u16    u16x4  __attribute__((ext_vector_type(4)));
typedef u16    u16x8  __attribute__((ext_vector_type(8)));

__device__ __forceinline__ u16 f2b(float f) {
    __hip_bfloat16 h = __float2bfloat16(f);
    return *reinterpret_cast<u16*>(&h);
}
__device__ __forceinline__ float b2f(u16 u) {
    unsigned int x = ((unsigned int)u) << 16;
    return __uint_as_float(x);
}

// tanh-form gelu folded into exp2: ~6 VALU ops, err ~1e-3 << bf16 noise.
__device__ __forceinline__ float fast_gelu(float v) {
    float t = v * v;
    float z = v * fmaf(0.10294294f, t, 2.30211842f);
    float e = exp2f(-z);
    return v * __builtin_amdgcn_rcpf(1.0f + e);
}

// async 16B global -> LDS. lds base wave-uniform; HW adds lane*16.
__device__ __forceinline__ void stage16(u16* lds_base_uniform, const u16* g, int lane) {
#if __has_builtin(__builtin_amdgcn_global_load_lds)
    __builtin_amdgcn_global_load_lds(
        (const __attribute__((address_space(1))) void*)g,
        (__attribute__((address_space(3))) void*)lds_base_uniform,
        16, 0, 0);
#else
    *(i32x4*)(lds_base_uniform + lane * 8) = *(const i32x4*)g;
#endif
}

// ---------------- prep mega-kernel: 6 weight transposes + LN1 ----------------
// blocks [0,16384): LN1 row z.  [16384, 16384+2304): four 768x768 transposes.
// [+2304, +4608): W1 [768][3072]->[3072][768].  [+4608, +6912): W2 [3072][768]->[768][3072].
struct PrepArgs {
    const float *x, *g1, *b1, *Wq, *Wk, *Wv, *Wp, *W1, *W2;
    u16 *xn, *Wqt, *Wkt, *Wvt, *Wpt, *W1t, *W2t;
};

__device__ __forceinline__ void do_transpose(const float* in, u16* out, int R, int Cc,
                                             int bx, int by, int tid) {
    __shared__ float tile[32][33];
    int c0 = bx * 32, r0 = by * 32;
    int tx = tid & 31, ty = tid >> 5;
    for (int i = ty; i < 32; i += 8)
        tile[i][tx] = in[(long)(r0 + i) * Cc + c0 + tx];
    __syncthreads();
    for (int i = ty; i < 32; i += 8)
        out[(long)(c0 + i) * R + r0 + tx] = f2b(tile[tx][i]);
}

__global__ __launch_bounds__(256) void prep_kernel(PrepArgs a) {
    int z = blockIdx.x;
    int tid = threadIdx.x;
    if (z < 16384) {
        // LN1 row z: fp32 -> bf16
        const int C = 768;
        const float* xr = a.x + (long)z * C;
        float v0 = xr[tid], v1 = xr[tid + 256], v2 = xr[tid + 512];
        float s = v0 + v1 + v2;
        float sq = v0 * v0 + v1 * v1 + v2 * v2;
#pragma unroll
        for (int o = 32; o; o >>= 1) { s += __shfl_xor(s, o); sq += __shfl_xor(sq, o); }
        __shared__ float ss[4], sq2[4];
        int wv = tid >> 6;
        if ((tid & 63) == 0) { ss[wv] = s; sq2[wv] = sq; }
        __syncthreads();
        s = ss[0] + ss[1] + ss[2] + ss[3];
        sq = sq2[0] + sq2[1] + sq2[2] + sq2[3];
        float mu = s * (1.0f / 768.0f);
        float var = sq * (1.0f / 768.0f) - mu * mu;
        float rs = rsqrtf(var + 1e-5f);
        u16* orow = a.xn + (long)z * C;
        orow[tid]       = f2b((v0 - mu) * rs * a.g1[tid]       + a.b1[tid]);
        orow[tid + 256] = f2b((v1 - mu) * rs * a.g1[tid + 256] + a.b1[tid + 256]);
        orow[tid + 512] = f2b((v2 - mu) * rs * a.g1[tid + 512] + a.b1[tid + 512]);
    } else {
        int t = z - 16384;
        if (t < 2304) {
            int m = t / 576, tt = t % 576;
            const float* in = (m == 0) ? a.Wq : (m == 1) ? a.Wk : (m == 2) ? a.Wv : a.Wp;
            u16* out = (m == 0) ? a.Wqt : (m == 1) ? a.Wkt : (m == 2) ? a.Wvt : a.Wpt;
            do_transpose(in, out, 768, 768, tt % 24, tt / 24, tid);
        } else if (t < 4608) {
            int tt = t - 2304;
            do_transpose(a.W1, a.W1t, 768, 3072, tt % 96, tt / 96, tid);
        } else {
            int tt = t - 4608;
            do_transpose(a.W2, a.W2t, 3072, 768, tt % 24, tt / 24, tid);
        }
    }
}

// ---------------- LN2: bf16 input (shadow of out), bf16 output -----------------
__global__ __launch_bounds__(192) void ln2_kernel(const u16* __restrict__ xb,
                                                  const float* __restrict__ g,
                                                  const float* __restrict__ b,
                                                  u16* __restrict__ out) {
    const int C = 768;
    long row = blockIdx.x;
    int t = threadIdx.x;
    u16x4 raw = *(const u16x4*)(xb + row * C + t * 4);
    f32x4 v;
#pragma unroll
    for (int j = 0; j < 4; j++) v[j] = b2f(raw[j]);
    float s = v[0] + v[1] + v[2] + v[3];
    float sq = v[0] * v[0] + v[1] * v[1] + v[2] * v[2] + v[3] * v[3];
#pragma unroll
    for (int o = 32; o; o >>= 1) { s += __shfl_xor(s, o); sq += __shfl_xor(sq, o); }
    __shared__ float ss[3], sq2[3];
    int wv = t >> 6;
    if ((t & 63) == 0) { ss[wv] = s; sq2[wv] = sq; }
    __syncthreads();
    s = ss[0] + ss[1] + ss[2];
    sq = sq2[0] + sq2[1] + sq2[2];
    float mu = s * (1.0f / 768.0f);
    float var = sq * (1.0f / 768.0f) - mu * mu;
    float rs = rsqrtf(var + 1e-5f);
    f32x4 gv = *(const f32x4*)(g + t * 4);
    f32x4 bv = *(const f32x4*)(b + t * 4);
    u16x4 pk;
#pragma unroll
    for (int j = 0; j < 4; j++) pk[j] = f2b((v[j] - mu) * rs * gv[j] + bv[j]);
    *(u16x4*)(out + row * C + t * 4) = pk;
}

// ---------------- causal softmax over bf16 scores, in place (u16x8) --------
__global__ __launch_bounds__(256) void softmax_causal(u16* __restrict__ S) {
    const int T = 2048;
    long row = blockIdx.x;
    int t = (int)(row & (T - 1));
    int ncols = ((t >> 7) + 1) << 7;
    u16* p = S + row * T;
    int tid = threadIdx.x;
    int base = tid * 8;
    bool act = base < ncols;
    float v[8];
    float mx = -3.0e38f;
    if (act) {
        u16x8 raw = *(const u16x8*)(p + base);
#pragma unroll
        for (int j = 0; j < 8; j++) {
            int col = base + j;
            v[j] = (col <= t) ? b2f(raw[j]) : -3.0e38f;
            mx = fmaxf(mx, v[j]);
        }
    }
#pragma unroll
    for (int o = 32; o; o >>= 1) mx = fmaxf(mx, __shfl_xor(mx, o));
    __shared__ float sm[4], ssum[4];
    int wv = tid >> 6;
    if ((tid & 63) == 0) sm[wv] = mx;
    __syncthreads();
    mx = fmaxf(fmaxf(sm[0], sm[1]), fmaxf(sm[2], sm[3]));
    float s = 0.0f;
    if (act) {
#pragma unroll
        for (int j = 0; j < 8; j++) {
            int col = base + j;
            float e = (col <= t) ? __expf(v[j] - mx) : 0.0f;
            v[j] = e;
            s += e;
        }
    }
#pragma unroll
    for (int o = 32; o; o >>= 1) s += __shfl_xor(s, o);
    if ((tid & 63) == 0) ssum[wv] = s;
    __syncthreads();
    s = ssum[0] + ssum[1] + ssum[2] + ssum[3];
    float inv = 1.0f / s;
    if (act) {
        u16x8 pk;
#pragma unroll
        for (int j = 0; j < 8; j++) pk[j] = f2b(v[j] * inv);
        *(u16x8*)(p + base) = pk;
    }
}

// ---------------- bf16 GEMM: C[M,N] = A[M,K] @ Bt[N,K]^T -------------
// Phase-aware swizzle: chunk c of row r stored at slot c ^ (r&7) ^ ((r>>3)&3).
// EPI: 0 bf16 store (scaled); 2 bf16 gelu(acc+bias); 3 f32 resid+acc+bias;
//      4 fused-QKV split; 5 = EPI3 + bf16 shadow to Out2
// CAUSAL: 0 none; 1 skip tiles n0 >= m0+128; 2 K-loop limited to m0+128
#define BM 128
#define BN 128
#define BKT 64

template <int EPI, int CAUSAL>
__global__ __launch_bounds__(256, 4) void gemm_bt(const u16* __restrict__ A,
                                                  const u16* __restrict__ Bt,
                                                  void* __restrict__ Out,
                                                  void* __restrict__ Out2,
                                                  const float* __restrict__ bias,
                                                  const float* __restrict__ resid,
                                                  int M, int N, int K,
                                                  int lda, int ldb, int ldo,
                                                  long long sA, long long sB, long long sO,
                                                  float scale) {
    int bz = blockIdx.z;
    A += (long)bz * sA;
    Bt += (long)bz * sB;
    long obase = (long)bz * sO;

    // XCD-aware swizzle: contiguous x-major chunk per XCD (id%8 round-robin).
    int gx = gridDim.x;
    int nblk = gx * gridDim.y;
    int lin = blockIdx.y * gx + blockIdx.x;
    int chunk = nblk >> 3;
    int tile = (lin & 7) * chunk + (lin >> 3);
    int m0 = (tile / gx) * BM;
    int n0 = (tile % gx) * BN;

    if (CAUSAL == 1 && n0 >= m0 + BM) return;
    int kend = (CAUSAL == 2) ? ((K < m0 + BM) ? K : (m0 + BM)) : K;

    __shared__ __align__(16) u16 As[128 * 64];
    __shared__ __align__(16) u16 Bs[128 * 64];

    int tid = threadIdx.x;
    int lane = tid & 63;
    int l32 = lane & 31, kg = lane >> 5;
    int w = tid >> 6;
    int wm = (w >> 1) * 64, wn = (w & 1) * 64;

    // per-lane fragment row swizzle constants
    int rA0 = wm + l32, rA1 = wm + 32 + l32;
    int rB0 = wn + l32, rB1 = wn + 32 + l32;
    int swA0 = (rA0 & 7) ^ ((rA0 >> 3) & 3), swA1 = (rA1 & 7) ^ ((rA1 >> 3) & 3);
    int swB0 = (rB0 & 7) ^ ((rB0 >> 3) & 3), swB1 = (rB1 & 7) ^ ((rB1 >> 3) & 3);

    f32x16 acc[2][2] = {};

    for (int k0 = 0; k0 < kend; k0 += BKT) {
#pragma unroll
        for (int i = 0; i < 4; i++) {
            int ebase = i * 256 + w * 64;         // wave-uniform chunk base
            int e = ebase + lane;
            int row = e >> 3;
            int gc = (e & 7) ^ (row & 7) ^ ((row >> 3) & 3);
            stage16(As + ebase * 8, A + (long)(m0 + row) * lda + k0 + gc * 8, lane);
            stage16(Bs + ebase * 8, Bt + (long)(n0 + row) * ldb + k0 + gc * 8, lane);
        }
        __syncthreads();
#pragma unroll
        for (int kk = 0; kk < 4; kk++) {          // K-step of 16
            int c = (kk << 1) + kg;               // chunk column 0..7
            bf16x8 af[2], bf[2];
            af[0] = *(const bf16x8*)(As + rA0 * 64 + ((c ^ swA0) << 3));
            af[1] = *(const bf16x8*)(As + rA1 * 64 + ((c ^ swA1) << 3));
            bf[0] = *(const bf16x8*)(Bs + rB0 * 64 + ((c ^ swB0) << 3));
            bf[1] = *(const bf16x8*)(Bs + rB1 * 64 + ((c ^ swB1) << 3));
#pragma unroll
            for (int mt = 0; mt < 2; mt++)
#pragma unroll
                for (int nt = 0; nt < 2; nt++)
                    acc[mt][nt] = __builtin_amdgcn_mfma_f32_32x32x16_bf16(af[mt], bf[nt], acc[mt][nt], 0, 0, 0);
        }
        __syncthreads();
    }

    // C/D 32x32 layout: col = lane&31, row = (reg&3) + 8*(reg>>2) + 4*(lane>>5)
#pragma unroll
    for (int mt = 0; mt < 2; ++mt)
#pragma unroll
        for (int nt = 0; nt < 2; ++nt) {
            int col = n0 + wn + nt * 32 + l32;
            int rb = m0 + wm + mt * 32 + 4 * kg;
            f32x16 a = acc[mt][nt];
            if (EPI == 0) {
                u16* o = (u16*)Out + obase;
#pragma unroll
                for (int r = 0; r < 16; r++)
                    o[(long)(rb + (r & 3) + 8 * (r >> 2)) * ldo + col] = f2b(a[r] * scale);
            } else if (EPI == 2) {
                u16* o = (u16*)Out + obase;
                float bv = bias[col];
#pragma unroll
                for (int r = 0; r < 16; r++)
                    o[(long)(rb + (r & 3) + 8 * (r >> 2)) * ldo + col] = f2b(fast_gelu(a[r] + bv));
            } else if (EPI == 3 || EPI == 5) {
                float* o = (float*)Out + obase;
                u16* o2 = (u16*)Out2;
                float bv = bias[col];
#pragma unroll
                for (int r = 0; r < 16; r++) {
                    long idx = (long)(rb + (r & 3) + 8 * (r >> 2)) * ldo + col;
                    float val = resid[idx] + a[r] + bv;
                    o[idx] = val;
                    if (EPI == 5) o2[idx] = f2b(val);
                }
            } else { // EPI 4: fused QKV. col<1536 -> qk [M][1536]; else v -> vT[b][c][t]
                if (col < 1536) {
                    u16* o = (u16*)Out;
#pragma unroll
                    for (int r = 0; r < 16; r++)
                        o[(long)(rb + (r & 3) + 8 * (r >> 2)) * 1536 + col] = f2b(a[r]);
                } else {
                    u16* o = (u16*)Out2;
                    int c = col - 1536;
#pragma unroll
                    for (int gi = 0; gi < 4; gi++) {
                        int row = rb + 8 * gi;
                        int b = row >> 11, t = row & 2047;
                        u16x4 pk;
#pragma unroll
                        for (int j = 0; j < 4; j++) pk[j] = f2b(a[gi * 4 + j]);
                        *(u16x4*)(o + ((long)b * 768 + c) * 2048 + t) = pk;
                    }
                }
            }
        }
}

extern "C" void kernel_launch(void* const* d_in, const int* in_sizes, int n_in,
                              void* d_out, int out_size, void* d_ws, size_t ws_size,
                              hipStream_t stream) {
    (void)in_sizes; (void)n_in; (void)out_size; (void)ws_size;
    const float* x   = (const float*)d_in[0];
    const float* Wq  = (const float*)d_in[1];
    const float* Wk  = (const float*)d_in[2];
    const float* Wv  = (const float*)d_in[3];
    const float* Wp  = (const float*)d_in[4];
    const float* bp  = (const float*)d_in[5];
    const float* g1  = (const float*)d_in[6];
    const float* b1  = (const float*)d_in[7];
    const float* g2  = (const float*)d_in[8];
    const float* b2  = (const float*)d_in[9];
    const float* W1  = (const float*)d_in[10];
    const float* bm1 = (const float*)d_in[11];
    const float* W2  = (const float*)d_in[12];
    const float* bm2 = (const float*)d_in[13];
    float* out = (float*)d_out;

    const int Bn = 8, T = 2048, C = 768, F = 3072;
    const int M = Bn * T; // 16384

    char* ws = (char*)d_ws;
    u16* xn = (u16*)(ws);
    u16* QK = (u16*)(ws + 25165824);   // [16384][1536]: q | k
    u16* vT = (u16*)(ws + 75497472);   // [8][768][2048]
    u16* S  = (u16*)(ws + 100663296);  // [8][2048][2048]
    u16* xb = (u16*)(ws + 100663296);  // bf16 shadow of proj out (S dead by then)
    u16* y  = (u16*)(ws + 167772160);
    u16* h1 = (u16*)(ws + 25165824);   // aliases QK/vT, dead by MLP
    u16* wgt = (u16*)(ws + 192937984);
    u16* Wqt = wgt;                     // [2304][768] fused qkv^T (q|k|v rows)
    u16* Wkt = Wqt + 589824;
    u16* Wvt = Wkt + 589824;
    u16* Wpt = Wvt + 589824;
    u16* W1t = Wpt + 589824;            // [3072][768]
    u16* W2t = W1t + (long)C * F;       // [768][3072]

    // prep: all weight transposes + LN1 in one launch
    PrepArgs pa{x, g1, b1, Wq, Wk, Wv, Wp, W1, W2, xn, Wqt, Wkt, Wvt, Wpt, W1t, W2t};
    hipLaunchKernelGGL(prep_kernel, dim3(16384 + 6912), dim3(256), 0, stream, pa);

    // Fused QKV: [q|k] -> QK [M][1536], v -> vT [8][768][2048]
    hipLaunchKernelGGL((gemm_bt<4, 0>), dim3((3 * C) / BN, M / BM, 1), dim3(256), 0, stream,
                       xn, Wqt, (void*)QK, (void*)vT, nullptr, nullptr,
                       M, 3 * C, C, C, C, 0, 0LL, 0LL, 0LL, 1.0f);

    // S = scale * q @ k^T (causal tile pruning), bf16
    float scl = 1.0f / sqrtf((float)C);
    hipLaunchKernelGGL((gemm_bt<0, 1>), dim3(T / BN, T / BM, Bn), dim3(256), 0, stream,
                       QK, QK + 768, (void*)S, nullptr, nullptr, nullptr,
                       T, T, C, 1536, 1536, T,
                       (long long)T * 1536, (long long)T * 1536, (long long)T * T, scl);

    // causal softmax in place (live region only)
    hipLaunchKernelGGL(softmax_causal, dim3(M), dim3(256), 0, stream, S);

    // y = P @ V  (Bt = vT, K limited to m0+128)
    hipLaunchKernelGGL((gemm_bt<0, 2>), dim3(C / BN, T / BM, Bn), dim3(256), 0, stream,
                       S, vT, (void*)y, nullptr, nullptr, nullptr,
                       T, C, T, T, T, C,
                       (long long)T * T, (long long)C * T, (long long)T * C, 1.0f);

    // out = x + y@Wp + bp (fp32) + bf16 shadow xb
    hipLaunchKernelGGL((gemm_bt<5, 0>), dim3(C / BN, M / BM, 1), dim3(256), 0, stream,
                       y, Wpt, (void*)out, (void*)xb, bp, x,
                       M, C, C, C, C, C, 0LL, 0LL, 0LL, 1.0f);

    // LN2 from bf16 shadow
    hipLaunchKernelGGL(ln2_kernel, dim3(M), dim3(192), 0, stream, xb, g2, b2, xn);

    // h1 = gelu(xn2@W1 + bm1)  bf16
    hipLaunchKernelGGL((gemm_bt<2, 0>), dim3(F / BN, M / BM, 1), dim3(256), 0, stream,
                       xn, W1t, (void*)h1, nullptr, bm1, nullptr,
                       M, F, C, C, C, F, 0LL, 0LL, 0LL, 1.0f);

    // out = out + h1@W2 + bm2
    hipLaunchKernelGGL((gemm_bt<3, 0>), dim3(C / BN, M / BM, 1), dim3(256), 0, stream,
                       h1, W2t, (void*)out, nullptr, bm2, out,
                       M, C, F, F, F, C, 0LL, 0LL, 0LL, 1.0f);
}

// Round 6
// 605.219 us; speedup vs baseline: 1.0726x; 1.0726x over previous
//
#include <hip/hip_runtime.h>
#include <hip/hip_bf16.h>

// Transformer block: x:[8,2048,768] fp32. All GEMMs in bf16 MFMA (fp32 acc).
// GEMM: 128x128x64 tiles, 32x32x16 MFMA (2x2/wave), global_load_lds dwordx4,
// phase-aware XOR swizzle (c ^ (r&7) ^ ((r>>3)&3)) -> 0 bank conflicts,
// XCD block swizzle, lb(256,4).
// Workspace layout (bytes):
//   [0          ) xn / xn2 bf16        25,165,824
//   [25165824   ) QK bf16 [16384][1536] 50,331,648   (aliased later by h1)
//   [75497472   ) vT bf16 [8][768][2048] 25,165,824  (h1)
//   [100663296  ) S/P bf16 [8][2048][2048] 67,108,864 (dead by MLP)
//   [167772160  ) y bf16               25,165,824
//   [192937984  ) bf16 weights         14,155,776
// total: 207,093,760 bytes

typedef unsigned short u16;
typedef __bf16 bf16x8 __attribute__((ext_vector_type(8)));
typedef float  f32x4  __attribute__((ext_vector_type(4)));
typedef float  f32x16 __attribute__((ext_vector_type(16)));
typedef int    i32x4  __attribute__((ext_vector_type(4)));
typedef u16    u16x4  __attribute__((ext_vector_type(4)));
typedef u16    u16x8  __attribute__((ext_vector_type(8)));

__device__ __forceinline__ u16 f2b(float f) {
    __hip_bfloat16 h = __float2bfloat16(f);
    return *reinterpret_cast<u16*>(&h);
}
__device__ __forceinline__ float b2f(u16 u) {
    unsigned int x = ((unsigned int)u) << 16;
    return __uint_as_float(x);
}

// tanh-form gelu folded into exp2: ~6 VALU ops, err ~1e-3 << bf16 noise.
__device__ __forceinline__ float fast_gelu(float v) {
    float t = v * v;
    float z = v * fmaf(0.10294294f, t, 2.30211842f);
    float e = exp2f(-z);
    return v * __builtin_amdgcn_rcpf(1.0f + e);
}

// async 16B global -> LDS. lds base wave-uniform; HW adds lane*16.
__device__ __forceinline__ void stage16(u16* lds_base_uniform, const u16* g, int lane) {
#if __has_builtin(__builtin_amdgcn_global_load_lds)
    __builtin_amdgcn_global_load_lds(
        (const __attribute__((address_space(1))) void*)g,
        (__attribute__((address_space(3))) void*)lds_base_uniform,
        16, 0, 0);
#else
    *(i32x4*)(lds_base_uniform + lane * 8) = *(const i32x4*)g;
#endif
}

// ---------------- batched weight transpose+cast: 6 matrices, one launch ----------------
// blocks [0,2304): four 768x768 (Wq,Wk,Wv,Wp). [2304,4608): W1 [768][3072]->[3072][768].
// [4608,6912): W2 [3072][768]->[768][3072].
struct TpArgs {
    const float *Wq, *Wk, *Wv, *Wp, *W1, *W2;
    u16 *Wqt, *Wkt, *Wvt, *Wpt, *W1t, *W2t;
};

__device__ __forceinline__ void do_transpose(const float* in, u16* out, int R, int Cc,
                                             int bx, int by, int tid) {
    __shared__ float tile[32][33];
    int c0 = bx * 32, r0 = by * 32;
    int tx = tid & 31, ty = tid >> 5;
    for (int i = ty; i < 32; i += 8)
        tile[i][tx] = in[(long)(r0 + i) * Cc + c0 + tx];
    __syncthreads();
    for (int i = ty; i < 32; i += 8)
        out[(long)(c0 + i) * R + r0 + tx] = f2b(tile[tx][i]);
}

__global__ __launch_bounds__(256) void transpose_batch(TpArgs a) {
    int z = blockIdx.x;
    int tid = threadIdx.x;
    if (z < 2304) {
        int m = z / 576, tt = z % 576;
        const float* in = (m == 0) ? a.Wq : (m == 1) ? a.Wk : (m == 2) ? a.Wv : a.Wp;
        u16* out = (m == 0) ? a.Wqt : (m == 1) ? a.Wkt : (m == 2) ? a.Wvt : a.Wpt;
        do_transpose(in, out, 768, 768, tt % 24, tt / 24, tid);
    } else if (z < 4608) {
        int tt = z - 2304;
        do_transpose(a.W1, a.W1t, 768, 3072, tt % 96, tt / 96, tid);
    } else {
        int tt = z - 4608;
        do_transpose(a.W2, a.W2t, 3072, 768, tt % 24, tt / 24, tid);
    }
}

// ---------------- layernorm fp32 -> bf16 (float4 vectorized, 192 thr) -----------------
__global__ __launch_bounds__(192) void ln_kernel(const float* __restrict__ x,
                                                 const float* __restrict__ g,
                                                 const float* __restrict__ b,
                                                 u16* __restrict__ out) {
    const int C = 768;
    long row = blockIdx.x;
    const float* xr = x + row * C;
    int t = threadIdx.x;
    f32x4 v = *(const f32x4*)(xr + t * 4);
    float s = v[0] + v[1] + v[2] + v[3];
    float sq = v[0] * v[0] + v[1] * v[1] + v[2] * v[2] + v[3] * v[3];
#pragma unroll
    for (int o = 32; o; o >>= 1) { s += __shfl_xor(s, o); sq += __shfl_xor(sq, o); }
    __shared__ float ss[3], sq2[3];
    int wv = t >> 6;
    if ((t & 63) == 0) { ss[wv] = s; sq2[wv] = sq; }
    __syncthreads();
    s = ss[0] + ss[1] + ss[2];
    sq = sq2[0] + sq2[1] + sq2[2];
    float mu = s * (1.0f / 768.0f);
    float var = sq * (1.0f / 768.0f) - mu * mu;
    float rs = rsqrtf(var + 1e-5f);
    f32x4 gv = *(const f32x4*)(g + t * 4);
    f32x4 bv = *(const f32x4*)(b + t * 4);
    u16x4 pk;
#pragma unroll
    for (int j = 0; j < 4; j++) pk[j] = f2b((v[j] - mu) * rs * gv[j] + bv[j]);
    *(u16x4*)(out + row * C + t * 4) = pk;
}

// ---------------- causal softmax over bf16 scores, in place (u16x8) --------
// Only the live region [0, ((t>>7)+1)<<7) is read/written; PV's K-limit reads exactly that.
__global__ __launch_bounds__(256) void softmax_causal(u16* __restrict__ S) {
    const int T = 2048;
    long row = blockIdx.x;
    int t = (int)(row & (T - 1));
    int ncols = ((t >> 7) + 1) << 7;
    u16* p = S + row * T;
    int tid = threadIdx.x;
    int base = tid * 8;
    bool act = base < ncols;
    float v[8];
    float mx = -3.0e38f;
    if (act) {
        u16x8 raw = *(const u16x8*)(p + base);
#pragma unroll
        for (int j = 0; j < 8; j++) {
            int col = base + j;
            v[j] = (col <= t) ? b2f(raw[j]) : -3.0e38f;
            mx = fmaxf(mx, v[j]);
        }
    }
#pragma unroll
    for (int o = 32; o; o >>= 1) mx = fmaxf(mx, __shfl_xor(mx, o));
    __shared__ float sm[4], ssum[4];
    int wv = tid >> 6;
    if ((tid & 63) == 0) sm[wv] = mx;
    __syncthreads();
    mx = fmaxf(fmaxf(sm[0], sm[1]), fmaxf(sm[2], sm[3]));
    float s = 0.0f;
    if (act) {
#pragma unroll
        for (int j = 0; j < 8; j++) {
            int col = base + j;
            float e = (col <= t) ? __expf(v[j] - mx) : 0.0f;
            v[j] = e;
            s += e;
        }
    }
#pragma unroll
    for (int o = 32; o; o >>= 1) s += __shfl_xor(s, o);
    if ((tid & 63) == 0) ssum[wv] = s;
    __syncthreads();
    s = ssum[0] + ssum[1] + ssum[2] + ssum[3];
    float inv = 1.0f / s;
    if (act) {
        u16x8 pk;
#pragma unroll
        for (int j = 0; j < 8; j++) pk[j] = f2b(v[j] * inv);
        *(u16x8*)(p + base) = pk;
    }
}

// ---------------- bf16 GEMM: C[M,N] = A[M,K] @ Bt[N,K]^T -------------
// Phase-aware swizzle: chunk c of row r stored at slot c ^ (r&7) ^ ((r>>3)&3).
// EPI: 0 bf16 store (scaled); 2 bf16 gelu(acc+bias); 3 f32 resid+acc+bias;
//      4 fused-QKV split (qk row-major ld 1536, v->vT)
// CAUSAL: 0 none; 1 skip tiles n0 >= m0+128; 2 K-loop limited to m0+128
#define BM 128
#define BN 128
#define BKT 64

template <int EPI, int CAUSAL>
__global__ __launch_bounds__(256, 4) void gemm_bt(const u16* __restrict__ A,
                                                  const u16* __restrict__ Bt,
                                                  void* __restrict__ Out,
                                                  void* __restrict__ Out2,
                                                  const float* __restrict__ bias,
                                                  const float* __restrict__ resid,
                                                  int M, int N, int K,
                                                  int lda, int ldb, int ldo,
                                                  long long sA, long long sB, long long sO,
                                                  float scale) {
    int bz = blockIdx.z;
    A += (long)bz * sA;
    Bt += (long)bz * sB;
    long obase = (long)bz * sO;

    // XCD-aware swizzle: contiguous x-major chunk per XCD (id%8 round-robin).
    int gx = gridDim.x;
    int nblk = gx * gridDim.y;
    int lin = blockIdx.y * gx + blockIdx.x;
    int chunk = nblk >> 3;
    int tile = (lin & 7) * chunk + (lin >> 3);
    int m0 = (tile / gx) * BM;
    int n0 = (tile % gx) * BN;

    if (CAUSAL == 1 && n0 >= m0 + BM) return;
    int kend = (CAUSAL == 2) ? ((K < m0 + BM) ? K : (m0 + BM)) : K;

    __shared__ __align__(16) u16 As[128 * 64];
    __shared__ __align__(16) u16 Bs[128 * 64];

    int tid = threadIdx.x;
    int lane = tid & 63;
    int l32 = lane & 31, kg = lane >> 5;
    int w = tid >> 6;
    int wm = (w >> 1) * 64, wn = (w & 1) * 64;

    // per-lane fragment row + swizzle constants
    int rA0 = wm + l32, rA1 = wm + 32 + l32;
    int rB0 = wn + l32, rB1 = wn + 32 + l32;
    int swA0 = (rA0 & 7) ^ ((rA0 >> 3) & 3), swA1 = (rA1 & 7) ^ ((rA1 >> 3) & 3);
    int swB0 = (rB0 & 7) ^ ((rB0 >> 3) & 3), swB1 = (rB1 & 7) ^ ((rB1 >> 3) & 3);

    f32x16 acc[2][2] = {};

    for (int k0 = 0; k0 < kend; k0 += BKT) {
#pragma unroll
        for (int i = 0; i < 4; i++) {
            int ebase = i * 256 + w * 64;         // wave-uniform chunk base
            int e = ebase + lane;
            int row = e >> 3;
            int gc = (e & 7) ^ (row & 7) ^ ((row >> 3) & 3);
            stage16(As + ebase * 8, A + (long)(m0 + row) * lda + k0 + gc * 8, lane);
            stage16(Bs + ebase * 8, Bt + (long)(n0 + row) * ldb + k0 + gc * 8, lane);
        }
        __syncthreads();
#pragma unroll
        for (int kk = 0; kk < 4; kk++) {          // K-step of 16
            int c = (kk << 1) + kg;               // chunk column 0..7
            bf16x8 af[2], bf[2];
            af[0] = *(const bf16x8*)(As + rA0 * 64 + ((c ^ swA0) << 3));
            af[1] = *(const bf16x8*)(As + rA1 * 64 + ((c ^ swA1) << 3));
            bf[0] = *(const bf16x8*)(Bs + rB0 * 64 + ((c ^ swB0) << 3));
            bf[1] = *(const bf16x8*)(Bs + rB1 * 64 + ((c ^ swB1) << 3));
#pragma unroll
            for (int mt = 0; mt < 2; mt++)
#pragma unroll
                for (int nt = 0; nt < 2; nt++)
                    acc[mt][nt] = __builtin_amdgcn_mfma_f32_32x32x16_bf16(af[mt], bf[nt], acc[mt][nt], 0, 0, 0);
        }
        __syncthreads();
    }

    // C/D 32x32 layout: col = lane&31, row = (reg&3) + 8*(reg>>2) + 4*(lane>>5)
#pragma unroll
    for (int mt = 0; mt < 2; ++mt)
#pragma unroll
        for (int nt = 0; nt < 2; ++nt) {
            int col = n0 + wn + nt * 32 + l32;
            int rb = m0 + wm + mt * 32 + 4 * kg;
            f32x16 a = acc[mt][nt];
            if (EPI == 0) {
                u16* o = (u16*)Out + obase;
#pragma unroll
                for (int r = 0; r < 16; r++)
                    o[(long)(rb + (r & 3) + 8 * (r >> 2)) * ldo + col] = f2b(a[r] * scale);
            } else if (EPI == 2) {
                u16* o = (u16*)Out + obase;
                float bv = bias[col];
#pragma unroll
                for (int r = 0; r < 16; r++)
                    o[(long)(rb + (r & 3) + 8 * (r >> 2)) * ldo + col] = f2b(fast_gelu(a[r] + bv));
            } else if (EPI == 3) {
                float* o = (float*)Out + obase;
                float bv = bias[col];
#pragma unroll
                for (int r = 0; r < 16; r++) {
                    long idx = (long)(rb + (r & 3) + 8 * (r >> 2)) * ldo + col;
                    o[idx] = resid[idx] + a[r] + bv;
                }
            } else { // EPI 4: fused QKV. col<1536 -> qk [M][1536]; else v -> vT[b][c][t]
                if (col < 1536) {
                    u16* o = (u16*)Out;
#pragma unroll
                    for (int r = 0; r < 16; r++)
                        o[(long)(rb + (r & 3) + 8 * (r >> 2)) * 1536 + col] = f2b(a[r]);
                } else {
                    u16* o = (u16*)Out2;
                    int c = col - 1536;
#pragma unroll
                    for (int gi = 0; gi < 4; gi++) {
                        int row = rb + 8 * gi;
                        int b = row >> 11, t = row & 2047;
                        u16x4 pk;
#pragma unroll
                        for (int j = 0; j < 4; j++) pk[j] = f2b(a[gi * 4 + j]);
                        *(u16x4*)(o + ((long)b * 768 + c) * 2048 + t) = pk;
                    }
                }
            }
        }
}

extern "C" void kernel_launch(void* const* d_in, const int* in_sizes, int n_in,
                              void* d_out, int out_size, void* d_ws, size_t ws_size,
                              hipStream_t stream) {
    (void)in_sizes; (void)n_in; (void)out_size; (void)ws_size;
    const float* x   = (const float*)d_in[0];
    const float* Wq  = (const float*)d_in[1];
    const float* Wk  = (const float*)d_in[2];
    const float* Wv  = (const float*)d_in[3];
    const float* Wp  = (const float*)d_in[4];
    const float* bp  = (const float*)d_in[5];
    const float* g1  = (const float*)d_in[6];
    const float* b1  = (const float*)d_in[7];
    const float* g2  = (const float*)d_in[8];
    const float* b2  = (const float*)d_in[9];
    const float* W1  = (const float*)d_in[10];
    const float* bm1 = (const float*)d_in[11];
    const float* W2  = (const float*)d_in[12];
    const float* bm2 = (const float*)d_in[13];
    float* out = (float*)d_out;

    const int Bn = 8, T = 2048, C = 768, F = 3072;
    const int M = Bn * T; // 16384

    char* ws = (char*)d_ws;
    u16* xn = (u16*)(ws);
    u16* QK = (u16*)(ws + 25165824);   // [16384][1536]: q | k
    u16* vT = (u16*)(ws + 75497472);   // [8][768][2048]
    u16* S  = (u16*)(ws + 100663296);  // [8][2048][2048]
    u16* y  = (u16*)(ws + 167772160);
    u16* h1 = (u16*)(ws + 25165824);   // aliases QK/vT, dead by MLP
    u16* wgt = (u16*)(ws + 192937984);
    u16* Wqt = wgt;                     // [2304][768] fused qkv^T (q|k|v rows)
    u16* Wkt = Wqt + 589824;
    u16* Wvt = Wkt + 589824;
    u16* Wpt = Wvt + 589824;
    u16* W1t = Wpt + 589824;            // [3072][768]
    u16* W2t = W1t + (long)C * F;       // [768][3072]

    // all 6 weight transposes in one launch
    TpArgs ta{Wq, Wk, Wv, Wp, W1, W2, Wqt, Wkt, Wvt, Wpt, W1t, W2t};
    hipLaunchKernelGGL(transpose_batch, dim3(6912), dim3(256), 0, stream, ta);

    // LN1
    hipLaunchKernelGGL(ln_kernel, dim3(M), dim3(192), 0, stream, x, g1, b1, xn);

    // Fused QKV: [q|k] -> QK [M][1536], v -> vT [8][768][2048]
    hipLaunchKernelGGL((gemm_bt<4, 0>), dim3((3 * C) / BN, M / BM, 1), dim3(256), 0, stream,
                       xn, Wqt, (void*)QK, (void*)vT, nullptr, nullptr,
                       M, 3 * C, C, C, C, 0, 0LL, 0LL, 0LL, 1.0f);

    // S = scale * q @ k^T (causal tile pruning), bf16
    float scl = 1.0f / sqrtf((float)C);
    hipLaunchKernelGGL((gemm_bt<0, 1>), dim3(T / BN, T / BM, Bn), dim3(256), 0, stream,
                       QK, QK + 768, (void*)S, nullptr, nullptr, nullptr,
                       T, T, C, 1536, 1536, T,
                       (long long)T * 1536, (long long)T * 1536, (long long)T * T, scl);

    // causal softmax in place (live region only)
    hipLaunchKernelGGL(softmax_causal, dim3(M), dim3(256), 0, stream, S);

    // y = P @ V  (Bt = vT, K limited to m0+128)
    hipLaunchKernelGGL((gemm_bt<0, 2>), dim3(C / BN, T / BM, Bn), dim3(256), 0, stream,
                       S, vT, (void*)y, nullptr, nullptr, nullptr,
                       T, C, T, T, T, C,
                       (long long)T * T, (long long)C * T, (long long)T * C, 1.0f);

    // out = x + y@Wp + bp   (fp32)
    hipLaunchKernelGGL((gemm_bt<3, 0>), dim3(C / BN, M / BM, 1), dim3(256), 0, stream,
                       y, Wpt, (void*)out, nullptr, bp, x,
                       M, C, C, C, C, C, 0LL, 0LL, 0LL, 1.0f);

    // LN2 (reads fp32 out)
    hipLaunchKernelGGL(ln_kernel, dim3(M), dim3(192), 0, stream, out, g2, b2, xn);

    // h1 = gelu(xn2@W1 + bm1)  bf16
    hipLaunchKernelGGL((gemm_bt<2, 0>), dim3(F / BN, M / BM, 1), dim3(256), 0, stream,
                       xn, W1t, (void*)h1, nullptr, bm1, nullptr,
                       M, F, C, C, C, F, 0LL, 0LL, 0LL, 1.0f);

    // out = out + h1@W2 + bm2
    hipLaunchKernelGGL((gemm_bt<3, 0>), dim3(C / BN, M / BM, 1), dim3(256), 0, stream,
                       h1, W2t, (void*)out, nullptr, bm2, out,
                       M, C, F, F, F, C, 0LL, 0LL, 0LL, 1.0f);
}